// Round 3
// baseline (1282.729 us; speedup 1.0000x reference)
//
#include <hip/hip_runtime.h>
#include <hip/hip_bf16.h>

// RGCN encoder: N=100000, E=128, R=9, L=3, NE=640000. Only the LAST layer
// matters (reference resets hidden=embeddings each layer).
//   out[n] = sum_{e:dst=n}(W_t h[src]+b_t) + sum_{e:src=n}(W_{t+9} h[dst]+b_{t+9})
// Fast path: (1) swizzle last-layer W into MFMA-fragment order (bf16),
// (2) gemm_all: per 64-row tile stage A once, loop 18 relations (MFMA),
//     bias folded, bf16 ht[18][Nn][128] written via wave-private LDS,
// (3) CSR build (count/scan/fill) of incoming-message row ids per node,
// (4) k_gather: one wave per node sums its ht rows, writes out once.

#define E_DIM 128
#define R_REL 9
#define GBM 64

typedef __attribute__((ext_vector_type(8))) short short8v;
typedef __attribute__((ext_vector_type(4))) float f32x4;

static __device__ __forceinline__ unsigned short f2bf(float f) {
    union { float f; unsigned u; } v; v.f = f;
    unsigned u = v.u;
    return (unsigned short)((u + 0x7FFFu + ((u >> 16) & 1u)) >> 16);
}
static __device__ __forceinline__ float bf2f(unsigned short h) {
    union { unsigned u; float f; } v; v.u = ((unsigned)h) << 16;
    return v.f;
}

// ---------- fast path ----------

// Wt[rel][w][s][c][lane][j] = bf16(W[rel][k=s*32+(lane>>4)*8+j][col=w*32+c*16+(lane&15)])
__global__ __launch_bounds__(256) void w_swizzle(
    const float* __restrict__ W18, unsigned short* __restrict__ Wt)
{
    const int rel = blockIdx.x;
    const float* __restrict__ Wr = W18 + (size_t)rel * E_DIM * E_DIM;
    const int tid = threadIdx.x;
#pragma unroll
    for (int k = 0; k < 8; k++) {
        int f = tid + k * 256;            // 0..2047
        int lane = f & 63;
        int c = (f >> 6) & 1;
        int s = (f >> 7) & 3;
        int w = (f >> 9) & 3;
        int col = w * 32 + c * 16 + (lane & 15);
        int kb = s * 32 + (lane >> 4) * 8;
        short8v v;
#pragma unroll
        for (int j = 0; j < 8; j++)
            v[j] = (short)f2bf(Wr[(size_t)(kb + j) * E_DIM + col]);
        *(short8v*)(Wt + ((size_t)((((rel * 4 + w) * 4 + s) * 2 + c) * 64 + lane)) * 8) = v;
    }
}

// One block per 64-row tile. Stage A once (fp32->bf16), then all 18 relations.
// No cross-wave barriers inside the rel loop: As is read-only, C staging is
// wave-private LDS.
__global__ __launch_bounds__(256) void gemm_all(
    const float* __restrict__ H, const unsigned short* __restrict__ Wt,
    const float* __restrict__ B18, unsigned short* __restrict__ htB, int Nn)
{
    __shared__ __align__(16) unsigned short As[GBM][136];
    __shared__ __align__(16) unsigned short Cs[4][GBM][36];

    const int tid = threadIdx.x;
    const int lane = tid & 63;
    const int w = tid >> 6;             // wave id, col slice w*32..w*32+31
    const int lr = lane & 15;
    const int lg = lane >> 4;
    const int n0 = blockIdx.x * GBM;

    // Stage A tile: 64 rows x 128 k, fp32 -> bf16, coalesced float4 reads.
#pragma unroll
    for (int j = 0; j < 8; j++) {
        int i = tid + j * 256;
        int row = i >> 5;
        int c4 = (i & 31) * 4;
        int n = n0 + row;
        float4 v = make_float4(0.f, 0.f, 0.f, 0.f);
        if (n < Nn) v = *(const float4*)(H + (size_t)n * E_DIM + c4);
        ushort4 b4;
        b4.x = f2bf(v.x); b4.y = f2bf(v.y); b4.z = f2bf(v.z); b4.w = f2bf(v.w);
        *(ushort4*)(&As[row][c4]) = b4;
    }
    __syncthreads();

    const short8v* wt8 = (const short8v*)Wt;

#pragma unroll 1
    for (int rel = 0; rel < 2 * R_REL; rel++) {
        // B fragments: 8 coalesced 16B loads per wave from swizzled Wt.
        short8v bfrag[4][2];
#pragma unroll
        for (int s = 0; s < 4; s++)
#pragma unroll
            for (int c = 0; c < 2; c++)
                bfrag[s][c] = wt8[(size_t)((((rel * 4 + w) * 4 + s) * 2 + c) * 64) + lane];

        float bias0 = B18[(size_t)rel * E_DIM + w * 32 + lr];
        float bias1 = B18[(size_t)rel * E_DIM + w * 32 + 16 + lr];

        f32x4 acc[4][2];
#pragma unroll
        for (int m = 0; m < 4; m++)
#pragma unroll
            for (int c = 0; c < 2; c++) acc[m][c] = (f32x4){0.f, 0.f, 0.f, 0.f};

#pragma unroll
        for (int s = 0; s < 4; s++)
#pragma unroll
            for (int m = 0; m < 4; m++) {
                short8v a = *(const short8v*)(&As[m * 16 + lr][s * 32 + lg * 8]);
#pragma unroll
                for (int c = 0; c < 2; c++)
                    acc[m][c] = __builtin_amdgcn_mfma_f32_16x16x32_bf16(
                        a, bfrag[s][c], acc[m][c], 0, 0, 0);
            }

        // Frags (+bias) -> wave-private LDS. D layout: col=lane&15, row=lg*4+q.
#pragma unroll
        for (int m = 0; m < 4; m++)
#pragma unroll
            for (int c = 0; c < 2; c++) {
                float bias = c ? bias1 : bias0;
#pragma unroll
                for (int q = 0; q < 4; q++)
                    Cs[w][m * 16 + lg * 4 + q][c * 16 + lr] = f2bf(acc[m][c][q] + bias);
            }

        // Wave-private copy LDS -> global (rows n0..n0+63, cols w*32..w*32+31).
        unsigned short* ho = htB + ((size_t)rel * Nn) * E_DIM;
#pragma unroll
        for (int j = 0; j < 4; j++) {
            int row = (lane >> 2) + j * 16;
            int ch = (lane & 3) * 8;
            int n = n0 + row;
            if (n < Nn) {
                short8v v = *(const short8v*)(&Cs[w][row][ch]);
                *(short8v*)(ho + (size_t)n * E_DIM + w * 32 + ch) = v;
            }
        }
    }
}

// CSR build: count (into off), single-block scan (off -> exclusive, cursor=off),
// fill records rec[pos] = rel*Nn + othernode.
__global__ __launch_bounds__(256) void k_count(
    const int* __restrict__ esrc, const int* __restrict__ edst,
    int* __restrict__ cnt, int ne)
{
    int e = blockIdx.x * 256 + threadIdx.x;
    if (e >= ne) return;
    atomicAdd(&cnt[edst[e]], 1);
    atomicAdd(&cnt[esrc[e]], 1);
}

__global__ __launch_bounds__(1024) void k_scan(
    int* __restrict__ off, int* __restrict__ cursor, int Nn)
{
    __shared__ int sh[1024];
    const int tid = threadIdx.x;
    const int chunk = (Nn + 1023) >> 10;
    const int base = tid * chunk;
    int lim = Nn - base;
    if (lim < 0) lim = 0;
    if (lim > chunk) lim = chunk;

    int s = 0;
    for (int j = 0; j < lim; j++) s += off[base + j];
    sh[tid] = s;
    __syncthreads();
    for (int o = 1; o < 1024; o <<= 1) {
        int v = (tid >= o) ? sh[tid - o] : 0;
        __syncthreads();
        sh[tid] += v;
        __syncthreads();
    }
    int run = sh[tid] - s;   // exclusive prefix for this chunk
    for (int j = 0; j < lim; j++) {
        int cv = off[base + j];
        off[base + j] = run;
        cursor[base + j] = run;
        run += cv;
    }
}

__global__ __launch_bounds__(256) void k_fill(
    const int* __restrict__ esrc, const int* __restrict__ edst,
    const int* __restrict__ etype, int* __restrict__ cursor,
    unsigned* __restrict__ rec, int ne, int Nn)
{
    int e = blockIdx.x * 256 + threadIdx.x;
    if (e >= ne) return;
    int t = etype[e], s = esrc[e], d = edst[e];
    int p = atomicAdd(&cursor[d], 1);
    rec[p] = (unsigned)(t * Nn + s);                 // forward message lands at d
    int p2 = atomicAdd(&cursor[s], 1);
    rec[p2] = (unsigned)((t + R_REL) * Nn + d);      // reverse message lands at s
}

// One wave per node: sum the bias-folded ht rows of its records, write once.
__global__ __launch_bounds__(256) void k_gather(
    const int* __restrict__ off, const int* __restrict__ cursor,
    const unsigned* __restrict__ rec, const unsigned short* __restrict__ htB,
    float* __restrict__ out, int Nn)
{
    int wid = blockIdx.x * 4 + (threadIdx.x >> 6);
    if (wid >= Nn) return;
    int lane = threadIdx.x & 63;
    int i = off[wid], end = cursor[wid];
    const ushort2* h2 = (const ushort2*)htB;
    float ax = 0.f, ay = 0.f;
    for (; i + 2 <= end; i += 2) {
        unsigned r0 = rec[i], r1 = rec[i + 1];
        ushort2 v0 = h2[(size_t)r0 * 64 + lane];
        ushort2 v1 = h2[(size_t)r1 * 64 + lane];
        ax += bf2f(v0.x) + bf2f(v1.x);
        ay += bf2f(v0.y) + bf2f(v1.y);
    }
    if (i < end) {
        ushort2 v = h2[(size_t)rec[i] * 64 + lane];
        ax += bf2f(v.x);
        ay += bf2f(v.y);
    }
    *(float2*)(out + (size_t)wid * E_DIM + 2 * lane) = make_float2(ax, ay);
}

// ---------- fallback path (round-2, validated) ----------

__global__ __launch_bounds__(256) void gemm_bf16(
    const float* __restrict__ H, const float* __restrict__ W18,
    const float* __restrict__ B18, unsigned short* __restrict__ htB,
    size_t bufstride, int p0, int Nn)
{
    __shared__ __align__(16) unsigned short As[GBM][136];

    const int b = blockIdx.y;
    const int rel = p0 + (b >> 1) + ((b & 1) ? R_REL : 0);
    const float* __restrict__ Wr = W18 + (size_t)rel * E_DIM * E_DIM;
    unsigned short* __restrict__ ho = htB + (size_t)b * bufstride;

    const int tid = threadIdx.x;
    const int lane = tid & 63;
    const int wc = (tid >> 6) * 32;
    const int lr = lane & 15;
    const int lg = lane >> 4;

    short8v bfrag[4][2];
#pragma unroll
    for (int s = 0; s < 4; s++)
#pragma unroll
        for (int c = 0; c < 2; c++) {
#pragma unroll
            for (int j = 0; j < 8; j++) {
                float wv = Wr[(size_t)(s * 32 + lg * 8 + j) * E_DIM + wc + c * 16 + lr];
                bfrag[s][c][j] = (short)f2bf(wv);
            }
        }
    const float bias0 = B18[(size_t)rel * E_DIM + wc + lr];
    const float bias1 = B18[(size_t)rel * E_DIM + wc + 16 + lr];

    const int ntiles = (Nn + GBM - 1) / GBM;
    for (int rt = blockIdx.x; rt < ntiles; rt += gridDim.x) {
        const int n0 = rt * GBM;
#pragma unroll
        for (int j = 0; j < 8; j++) {
            int i = tid + j * 256;
            int row = i >> 5;
            int c4 = (i & 31) * 4;
            int n = n0 + row;
            float4 v = make_float4(0.f, 0.f, 0.f, 0.f);
            if (n < Nn) v = *(const float4*)(H + (size_t)n * E_DIM + c4);
            ushort4 b4;
            b4.x = f2bf(v.x); b4.y = f2bf(v.y); b4.z = f2bf(v.z); b4.w = f2bf(v.w);
            *(ushort4*)(&As[row][c4]) = b4;
        }
        __syncthreads();

        f32x4 acc[4][2];
#pragma unroll
        for (int m = 0; m < 4; m++)
#pragma unroll
            for (int c = 0; c < 2; c++) acc[m][c] = (f32x4){0.f, 0.f, 0.f, 0.f};

#pragma unroll
        for (int s = 0; s < 4; s++)
#pragma unroll
            for (int m = 0; m < 4; m++) {
                short8v a = *(const short8v*)(&As[m * 16 + lr][s * 32 + lg * 8]);
#pragma unroll
                for (int c = 0; c < 2; c++)
                    acc[m][c] = __builtin_amdgcn_mfma_f32_16x16x32_bf16(
                        a, bfrag[s][c], acc[m][c], 0, 0, 0);
            }
        __syncthreads();

#pragma unroll
        for (int m = 0; m < 4; m++)
#pragma unroll
            for (int c = 0; c < 2; c++) {
                float bias = c ? bias1 : bias0;
#pragma unroll
                for (int q = 0; q < 4; q++)
                    As[m * 16 + lg * 4 + q][wc + c * 16 + lr] = f2bf(acc[m][c][q] + bias);
            }
        __syncthreads();

#pragma unroll
        for (int j = 0; j < 4; j++) {
            int i = tid + j * 256;
            int row = i >> 4;
            int c8 = (i & 15) * 8;
            int n = n0 + row;
            if (n < Nn) {
                short8v v = *(const short8v*)(&As[row][c8]);
                *(short8v*)(ho + (size_t)n * E_DIM + c8) = v;
            }
        }
        __syncthreads();
    }
}

__global__ __launch_bounds__(256) void scatter_grp(
    const int* __restrict__ esrc, const int* __restrict__ edst,
    const int* __restrict__ etype,
    const unsigned short* __restrict__ htB, size_t bufstride,
    float* __restrict__ out, int ne, int p0, int pg)
{
    int wid = blockIdx.x * 4 + (threadIdx.x >> 6);
    if (wid >= ne) return;
    int t = etype[wid];
    int q = t - p0;
    if ((unsigned)q >= (unsigned)pg) return;
    int lane = threadIdx.x & 63;
    int s = esrc[wid], d = edst[wid];

    const ushort2* vf = (const ushort2*)(htB + (size_t)(2 * q) * bufstride + (size_t)s * E_DIM);
    const ushort2* vb = (const ushort2*)(htB + (size_t)(2 * q + 1) * bufstride + (size_t)d * E_DIM);
    ushort2 a = vf[lane];
    ushort2 c = vb[lane];

    float* od = out + (size_t)d * E_DIM + 2 * lane;
    float* os = out + (size_t)s * E_DIM + 2 * lane;
    atomicAdd(od + 0, bf2f(a.x));
    atomicAdd(od + 1, bf2f(a.y));
    atomicAdd(os + 0, bf2f(c.x));
    atomicAdd(os + 1, bf2f(c.y));
}

__global__ __launch_bounds__(128) void direct_edge(
    const int* __restrict__ esrc, const int* __restrict__ edst,
    const int* __restrict__ etype,
    const float* __restrict__ H, const float* __restrict__ W2,
    const float* __restrict__ B2, float* __restrict__ out, int ne)
{
    __shared__ float hs[E_DIM];
    __shared__ float hd[E_DIM];
    int e = blockIdx.x;
    if (e >= ne) return;
    int t = etype[e], s = esrc[e], d = edst[e];
    int c = threadIdx.x;
    hs[c] = H[(size_t)s * E_DIM + c];
    hd[c] = H[(size_t)d * E_DIM + c];
    __syncthreads();
    const float* Wf = W2 + (size_t)t * E_DIM * E_DIM;
    const float* Wb = W2 + (size_t)(t + R_REL) * E_DIM * E_DIM;
    float accf = B2[(size_t)t * E_DIM + c];
    float accb = B2[(size_t)(t + R_REL) * E_DIM + c];
#pragma unroll 8
    for (int k = 0; k < E_DIM; k++) {
        accf += hs[k] * Wf[(size_t)k * E_DIM + c];
        accb += hd[k] * Wb[(size_t)k * E_DIM + c];
    }
    atomicAdd(&out[(size_t)d * E_DIM + c], accf);
    atomicAdd(&out[(size_t)s * E_DIM + c], accb);
}

extern "C" void kernel_launch(void* const* d_in, const int* in_sizes, int n_in,
                              void* d_out, int out_size, void* d_ws, size_t ws_size,
                              hipStream_t stream) {
    const int* edge_index = (const int*)d_in[0];   // [2][NE]
    const int* edge_type  = (const int*)d_in[1];   // [NE]
    const float* emb      = (const float*)d_in[2]; // [N][128]
    const float* weights  = (const float*)d_in[3]; // [L][18][128][128]
    const float* biases   = (const float*)d_in[4]; // [L][18][128]
    float* out = (float*)d_out;

    const int NE = in_sizes[1];
    const int Nn = in_sizes[2] / E_DIM;
    const int L  = in_sizes[3] / (2 * R_REL * E_DIM * E_DIM);

    const float* W2 = weights + (size_t)(L - 1) * 2 * R_REL * E_DIM * E_DIM;
    const float* B2 = biases  + (size_t)(L - 1) * 2 * R_REL * E_DIM;

    const int* esrc = edge_index;
    const int* edst = edge_index + NE;

    const size_t bufelems = (size_t)Nn * E_DIM;               // bf16 elements
    const size_t bufbytes = bufelems * sizeof(unsigned short);

    auto al = [](size_t x) { return (x + 255) & ~(size_t)255; };
    const size_t htBytes  = al(18 * bufbytes);
    const size_t wtBytes  = al((size_t)18 * E_DIM * E_DIM * 2);
    const size_t offBytes = al((size_t)Nn * 4);
    const size_t curBytes = al((size_t)Nn * 4);
    const size_t recBytes = al((size_t)2 * NE * 4);
    const size_t need = htBytes + wtBytes + offBytes + curBytes + recBytes;

    if (ws_size >= need) {
        char* p = (char*)d_ws;
        unsigned short* htB = (unsigned short*)p;        p += htBytes;
        unsigned short* Wt  = (unsigned short*)p;        p += wtBytes;
        int* off            = (int*)p;                   p += offBytes;
        int* cursor         = (int*)p;                   p += curBytes;
        unsigned* rec       = (unsigned*)p;

        hipMemsetAsync(off, 0, (size_t)Nn * 4, stream);
        k_count<<<(NE + 255) / 256, 256, 0, stream>>>(esrc, edst, off, NE);
        k_scan<<<1, 1024, 0, stream>>>(off, cursor, Nn);
        k_fill<<<(NE + 255) / 256, 256, 0, stream>>>(esrc, edst, edge_type,
                                                     cursor, rec, NE, Nn);
        w_swizzle<<<2 * R_REL, 256, 0, stream>>>(W2, Wt);
        gemm_all<<<(Nn + GBM - 1) / GBM, 256, 0, stream>>>(emb, Wt, B2, htB, Nn);
        k_gather<<<(Nn + 3) / 4, 256, 0, stream>>>(off, cursor, rec, htB, out, Nn);
        return;
    }

    // Fallbacks (round-2 behavior).
    hipMemsetAsync(d_out, 0, (size_t)Nn * E_DIM * sizeof(float), stream);
    const int nbuf = (int)(ws_size / bufbytes);
    if (nbuf >= 2) {
        const int PG = (nbuf / 2 < R_REL) ? (nbuf / 2) : R_REL;
        unsigned short* htB = (unsigned short*)d_ws;
        const int gx = (Nn + GBM * 4 - 1) / (GBM * 4);
        for (int p0 = 0; p0 < R_REL; ) {
            int pg = (R_REL - p0 < PG) ? (R_REL - p0) : PG;
            dim3 g1(gx, 2 * pg);
            gemm_bf16<<<g1, 256, 0, stream>>>(emb, W2, B2, htB, bufelems, p0, Nn);
            scatter_grp<<<(NE + 3) / 4, 256, 0, stream>>>(
                esrc, edst, edge_type, htB, bufelems, out, NE, p0, pg);
            p0 += pg;
        }
    } else {
        direct_edge<<<NE, 128, 0, stream>>>(esrc, edst, edge_type, emb, W2, B2, out, NE);
    }
}

// Round 4
// 924.154 us; speedup vs baseline: 1.3880x; 1.3880x over previous
//
#include <hip/hip_runtime.h>
#include <hip/hip_bf16.h>

// RGCN encoder: N=100000, E=128, R=9, L=3, NE=640000. Only the LAST layer
// matters (reference resets hidden=embeddings each layer).
//   out[n] = sum_{e:dst=n}(W_t h[src]+b_t) + sum_{e:src=n}(W_{t+9} h[dst]+b_{t+9})
// Fast path (needs ~238 MB ws; known ws >= 460.8 MB from round-2 behavior):
//  (1) w_swizzle: last-layer W -> MFMA B-fragment order, bf16 (0.59 MB, L2-hot)
//  (2) CSR build: per-(node, direction) record lists; rec = relInGroup*Nn+other
//  (3) two passes (fwd rels 0..8, bwd rels 9..17):
//      gemm_all9: per 64-row tile stage A once, 9 relations of MFMA, bias
//                 folded, bf16 ht[9][Nn][128] (230.4 MB)
//      k_gather:  one wave per node sums its ht rows, writes out once
//                 (pass 1 accumulates) -- NO atomics, no write amplification.

#define E_DIM 128
#define R_REL 9
#define GBM 64

typedef __attribute__((ext_vector_type(8))) short short8v;
typedef __attribute__((ext_vector_type(4))) float f32x4;

static __device__ __forceinline__ unsigned short f2bf(float f) {
    union { float f; unsigned u; } v; v.f = f;
    unsigned u = v.u;
    return (unsigned short)((u + 0x7FFFu + ((u >> 16) & 1u)) >> 16);
}
static __device__ __forceinline__ float bf2f(unsigned short h) {
    union { unsigned u; float f; } v; v.u = ((unsigned)h) << 16;
    return v.f;
}

// ---------- fast path ----------

// Wt[rel][w][s][c][lane][j] = bf16(W[rel][k=s*32+(lane>>4)*8+j][col=w*32+c*16+(lane&15)])
__global__ __launch_bounds__(256) void w_swizzle(
    const float* __restrict__ W18, unsigned short* __restrict__ Wt)
{
    const int rel = blockIdx.x;
    const float* __restrict__ Wr = W18 + (size_t)rel * E_DIM * E_DIM;
    const int tid = threadIdx.x;
#pragma unroll
    for (int k = 0; k < 8; k++) {
        int f = tid + k * 256;            // 0..2047
        int lane = f & 63;
        int c = (f >> 6) & 1;
        int s = (f >> 7) & 3;
        int w = (f >> 9) & 3;
        int col = w * 32 + c * 16 + (lane & 15);
        int kb = s * 32 + (lane >> 4) * 8;
        short8v v;
#pragma unroll
        for (int j = 0; j < 8; j++)
            v[j] = (short)f2bf(Wr[(size_t)(kb + j) * E_DIM + col]);
        *(short8v*)(Wt + ((size_t)((((rel * 4 + w) * 4 + s) * 2 + c) * 64 + lane)) * 8) = v;
    }
}

// One block per 64-row tile; stage A once (fp32->bf16), then 9 relations
// rbase..rbase+8 -> buffers q=0..8. No cross-wave barriers in the rel loop
// (As read-only after the single barrier; Cs staging is wave-private).
__global__ __launch_bounds__(256) void gemm_all9(
    const float* __restrict__ H, const unsigned short* __restrict__ Wt,
    const float* __restrict__ B18, unsigned short* __restrict__ htB,
    int Nn, int rbase)
{
    __shared__ __align__(16) unsigned short As[GBM][136];
    __shared__ __align__(16) unsigned short Cs[4][GBM][36];

    const int tid = threadIdx.x;
    const int lane = tid & 63;
    const int w = tid >> 6;             // wave id; col slice w*32..w*32+31
    const int lr = lane & 15;
    const int lg = lane >> 4;
    const int n0 = blockIdx.x * GBM;

    // Stage A tile: 64 rows x 128 k, fp32 -> bf16, coalesced float4 reads.
#pragma unroll
    for (int j = 0; j < 8; j++) {
        int i = tid + j * 256;
        int row = i >> 5;
        int c4 = (i & 31) * 4;
        int n = n0 + row;
        float4 v = make_float4(0.f, 0.f, 0.f, 0.f);
        if (n < Nn) v = *(const float4*)(H + (size_t)n * E_DIM + c4);
        ushort4 b4;
        b4.x = f2bf(v.x); b4.y = f2bf(v.y); b4.z = f2bf(v.z); b4.w = f2bf(v.w);
        *(ushort4*)(&As[row][c4]) = b4;
    }
    __syncthreads();

    const short8v* wt8 = (const short8v*)Wt;

#pragma unroll 1
    for (int q = 0; q < R_REL; q++) {
        const int rel = rbase + q;
        // B fragments: 8 coalesced 16B loads per wave from swizzled Wt.
        short8v bfrag[4][2];
#pragma unroll
        for (int s = 0; s < 4; s++)
#pragma unroll
            for (int c = 0; c < 2; c++)
                bfrag[s][c] = wt8[(size_t)((((rel * 4 + w) * 4 + s) * 2 + c) * 64) + lane];

        float bias0 = B18[(size_t)rel * E_DIM + w * 32 + lr];
        float bias1 = B18[(size_t)rel * E_DIM + w * 32 + 16 + lr];

        f32x4 acc[4][2];
#pragma unroll
        for (int m = 0; m < 4; m++)
#pragma unroll
            for (int c = 0; c < 2; c++) acc[m][c] = (f32x4){0.f, 0.f, 0.f, 0.f};

#pragma unroll
        for (int s = 0; s < 4; s++)
#pragma unroll
            for (int m = 0; m < 4; m++) {
                short8v a = *(const short8v*)(&As[m * 16 + lr][s * 32 + lg * 8]);
#pragma unroll
                for (int c = 0; c < 2; c++)
                    acc[m][c] = __builtin_amdgcn_mfma_f32_16x16x32_bf16(
                        a, bfrag[s][c], acc[m][c], 0, 0, 0);
            }

        // Frags (+bias) -> wave-private LDS. D layout: col=lane&15, row=lg*4+q.
#pragma unroll
        for (int m = 0; m < 4; m++)
#pragma unroll
            for (int c = 0; c < 2; c++) {
                float bias = c ? bias1 : bias0;
#pragma unroll
                for (int p = 0; p < 4; p++)
                    Cs[w][m * 16 + lg * 4 + p][c * 16 + lr] = f2bf(acc[m][c][p] + bias);
            }

        // Wave-private copy LDS -> global (rows n0..n0+63, cols w*32..+31).
        unsigned short* ho = htB + ((size_t)q * Nn) * E_DIM;
#pragma unroll
        for (int j = 0; j < 4; j++) {
            int row = (lane >> 2) + j * 16;
            int ch = (lane & 3) * 8;
            int n = n0 + row;
            if (n < Nn) {
                short8v v = *(const short8v*)(&Cs[w][row][ch]);
                *(short8v*)(ho + (size_t)n * E_DIM + w * 32 + ch) = v;
            }
        }
    }
}

// CSR build over 2*Nn segments: segment n       = forward messages into n (dst),
//                               segment Nn + n  = backward messages into n (src).
__global__ __launch_bounds__(256) void k_count(
    const int* __restrict__ esrc, const int* __restrict__ edst,
    int* __restrict__ cnt, int ne, int Nn)
{
    int e = blockIdx.x * 256 + threadIdx.x;
    if (e >= ne) return;
    atomicAdd(&cnt[edst[e]], 1);
    atomicAdd(&cnt[Nn + esrc[e]], 1);
}

__global__ __launch_bounds__(1024) void k_scan(
    int* __restrict__ off, int* __restrict__ cursor, int n2)
{
    __shared__ int sh[1024];
    const int tid = threadIdx.x;
    const int chunk = (n2 + 1023) >> 10;
    const int base = tid * chunk;
    int lim = n2 - base;
    if (lim < 0) lim = 0;
    if (lim > chunk) lim = chunk;

    int s = 0;
    for (int j = 0; j < lim; j++) s += off[base + j];
    sh[tid] = s;
    __syncthreads();
    for (int o = 1; o < 1024; o <<= 1) {
        int v = (tid >= o) ? sh[tid - o] : 0;
        __syncthreads();
        sh[tid] += v;
        __syncthreads();
    }
    int run = sh[tid] - s;   // exclusive prefix for this chunk
    for (int j = 0; j < lim; j++) {
        int cv = off[base + j];
        off[base + j] = run;
        cursor[base + j] = run;
        run += cv;
    }
}

// rec value = relInGroup*Nn + otherNode  (relInGroup = edge_type, both groups).
__global__ __launch_bounds__(256) void k_fill(
    const int* __restrict__ esrc, const int* __restrict__ edst,
    const int* __restrict__ etype, int* __restrict__ cursor,
    unsigned* __restrict__ rec, int ne, int Nn)
{
    int e = blockIdx.x * 256 + threadIdx.x;
    if (e >= ne) return;
    int t = etype[e], s = esrc[e], d = edst[e];
    int p = atomicAdd(&cursor[d], 1);
    rec[p] = (unsigned)(t * Nn + s);        // fwd: rel t (buffer t, pass 0)
    int p2 = atomicAdd(&cursor[Nn + s], 1);
    rec[p2] = (unsigned)(t * Nn + d);       // bwd: rel t+9 (buffer t, pass 1)
}

// One wave per node: sum bias-folded ht rows of segment base+wid; write once.
__global__ __launch_bounds__(256) void k_gather(
    const int* __restrict__ off, const int* __restrict__ cur,
    const unsigned* __restrict__ rec, const unsigned short* __restrict__ htB,
    float* __restrict__ out, int Nn, int base, int accum)
{
    int wid = blockIdx.x * 4 + (threadIdx.x >> 6);
    if (wid >= Nn) return;
    int lane = threadIdx.x & 63;
    int i = off[base + wid], end = cur[base + wid];
    const ushort2* h2 = (const ushort2*)htB;
    float ax = 0.f, ay = 0.f;
    if (accum) {
        float2 prev = *(const float2*)(out + (size_t)wid * E_DIM + 2 * lane);
        ax = prev.x; ay = prev.y;
    }
    for (; i + 2 <= end; i += 2) {
        unsigned r0 = rec[i], r1 = rec[i + 1];
        ushort2 v0 = h2[(size_t)r0 * 64 + lane];
        ushort2 v1 = h2[(size_t)r1 * 64 + lane];
        ax += bf2f(v0.x) + bf2f(v1.x);
        ay += bf2f(v0.y) + bf2f(v1.y);
    }
    if (i < end) {
        ushort2 v = h2[(size_t)rec[i] * 64 + lane];
        ax += bf2f(v.x);
        ay += bf2f(v.y);
    }
    *(float2*)(out + (size_t)wid * E_DIM + 2 * lane) = make_float2(ax, ay);
}

// ---------- fallback path (round-2, validated) ----------

__global__ __launch_bounds__(256) void gemm_bf16(
    const float* __restrict__ H, const float* __restrict__ W18,
    const float* __restrict__ B18, unsigned short* __restrict__ htB,
    size_t bufstride, int p0, int Nn)
{
    __shared__ __align__(16) unsigned short As[GBM][136];

    const int b = blockIdx.y;
    const int rel = p0 + (b >> 1) + ((b & 1) ? R_REL : 0);
    const float* __restrict__ Wr = W18 + (size_t)rel * E_DIM * E_DIM;
    unsigned short* __restrict__ ho = htB + (size_t)b * bufstride;

    const int tid = threadIdx.x;
    const int lane = tid & 63;
    const int wc = (tid >> 6) * 32;
    const int lr = lane & 15;
    const int lg = lane >> 4;

    short8v bfrag[4][2];
#pragma unroll
    for (int s = 0; s < 4; s++)
#pragma unroll
        for (int c = 0; c < 2; c++) {
#pragma unroll
            for (int j = 0; j < 8; j++) {
                float wv = Wr[(size_t)(s * 32 + lg * 8 + j) * E_DIM + wc + c * 16 + lr];
                bfrag[s][c][j] = (short)f2bf(wv);
            }
        }
    const float bias0 = B18[(size_t)rel * E_DIM + wc + lr];
    const float bias1 = B18[(size_t)rel * E_DIM + wc + 16 + lr];

    const int ntiles = (Nn + GBM - 1) / GBM;
    for (int rt = blockIdx.x; rt < ntiles; rt += gridDim.x) {
        const int n0 = rt * GBM;
#pragma unroll
        for (int j = 0; j < 8; j++) {
            int i = tid + j * 256;
            int row = i >> 5;
            int c4 = (i & 31) * 4;
            int n = n0 + row;
            float4 v = make_float4(0.f, 0.f, 0.f, 0.f);
            if (n < Nn) v = *(const float4*)(H + (size_t)n * E_DIM + c4);
            ushort4 b4;
            b4.x = f2bf(v.x); b4.y = f2bf(v.y); b4.z = f2bf(v.z); b4.w = f2bf(v.w);
            *(ushort4*)(&As[row][c4]) = b4;
        }
        __syncthreads();

        f32x4 acc[4][2];
#pragma unroll
        for (int m = 0; m < 4; m++)
#pragma unroll
            for (int c = 0; c < 2; c++) acc[m][c] = (f32x4){0.f, 0.f, 0.f, 0.f};

#pragma unroll
        for (int s = 0; s < 4; s++)
#pragma unroll
            for (int m = 0; m < 4; m++) {
                short8v a = *(const short8v*)(&As[m * 16 + lr][s * 32 + lg * 8]);
#pragma unroll
                for (int c = 0; c < 2; c++)
                    acc[m][c] = __builtin_amdgcn_mfma_f32_16x16x32_bf16(
                        a, bfrag[s][c], acc[m][c], 0, 0, 0);
            }
        __syncthreads();

#pragma unroll
        for (int m = 0; m < 4; m++)
#pragma unroll
            for (int c = 0; c < 2; c++) {
                float bias = c ? bias1 : bias0;
#pragma unroll
                for (int p = 0; p < 4; p++)
                    As[m * 16 + lg * 4 + p][wc + c * 16 + lr] = f2bf(acc[m][c][p] + bias);
            }
        __syncthreads();

#pragma unroll
        for (int j = 0; j < 4; j++) {
            int i = tid + j * 256;
            int row = i >> 4;
            int c8 = (i & 15) * 8;
            int n = n0 + row;
            if (n < Nn) {
                short8v v = *(const short8v*)(&As[row][c8]);
                *(short8v*)(ho + (size_t)n * E_DIM + c8) = v;
            }
        }
        __syncthreads();
    }
}

__global__ __launch_bounds__(256) void scatter_grp(
    const int* __restrict__ esrc, const int* __restrict__ edst,
    const int* __restrict__ etype,
    const unsigned short* __restrict__ htB, size_t bufstride,
    float* __restrict__ out, int ne, int p0, int pg)
{
    int wid = blockIdx.x * 4 + (threadIdx.x >> 6);
    if (wid >= ne) return;
    int t = etype[wid];
    int q = t - p0;
    if ((unsigned)q >= (unsigned)pg) return;
    int lane = threadIdx.x & 63;
    int s = esrc[wid], d = edst[wid];

    const ushort2* vf = (const ushort2*)(htB + (size_t)(2 * q) * bufstride + (size_t)s * E_DIM);
    const ushort2* vb = (const ushort2*)(htB + (size_t)(2 * q + 1) * bufstride + (size_t)d * E_DIM);
    ushort2 a = vf[lane];
    ushort2 c = vb[lane];

    float* od = out + (size_t)d * E_DIM + 2 * lane;
    float* os = out + (size_t)s * E_DIM + 2 * lane;
    atomicAdd(od + 0, bf2f(a.x));
    atomicAdd(od + 1, bf2f(a.y));
    atomicAdd(os + 0, bf2f(c.x));
    atomicAdd(os + 1, bf2f(c.y));
}

__global__ __launch_bounds__(128) void direct_edge(
    const int* __restrict__ esrc, const int* __restrict__ edst,
    const int* __restrict__ etype,
    const float* __restrict__ H, const float* __restrict__ W2,
    const float* __restrict__ B2, float* __restrict__ out, int ne)
{
    __shared__ float hs[E_DIM];
    __shared__ float hd[E_DIM];
    int e = blockIdx.x;
    if (e >= ne) return;
    int t = etype[e], s = esrc[e], d = edst[e];
    int c = threadIdx.x;
    hs[c] = H[(size_t)s * E_DIM + c];
    hd[c] = H[(size_t)d * E_DIM + c];
    __syncthreads();
    const float* Wf = W2 + (size_t)t * E_DIM * E_DIM;
    const float* Wb = W2 + (size_t)(t + R_REL) * E_DIM * E_DIM;
    float accf = B2[(size_t)t * E_DIM + c];
    float accb = B2[(size_t)(t + R_REL) * E_DIM + c];
#pragma unroll 8
    for (int k = 0; k < E_DIM; k++) {
        accf += hs[k] * Wf[(size_t)k * E_DIM + c];
        accb += hd[k] * Wb[(size_t)k * E_DIM + c];
    }
    atomicAdd(&out[(size_t)d * E_DIM + c], accf);
    atomicAdd(&out[(size_t)s * E_DIM + c], accb);
}

extern "C" void kernel_launch(void* const* d_in, const int* in_sizes, int n_in,
                              void* d_out, int out_size, void* d_ws, size_t ws_size,
                              hipStream_t stream) {
    const int* edge_index = (const int*)d_in[0];   // [2][NE]
    const int* edge_type  = (const int*)d_in[1];   // [NE]
    const float* emb      = (const float*)d_in[2]; // [N][128]
    const float* weights  = (const float*)d_in[3]; // [L][18][128][128]
    const float* biases   = (const float*)d_in[4]; // [L][18][128]
    float* out = (float*)d_out;

    const int NE = in_sizes[1];
    const int Nn = in_sizes[2] / E_DIM;
    const int L  = in_sizes[3] / (2 * R_REL * E_DIM * E_DIM);

    const float* W2 = weights + (size_t)(L - 1) * 2 * R_REL * E_DIM * E_DIM;
    const float* B2 = biases  + (size_t)(L - 1) * 2 * R_REL * E_DIM;

    const int* esrc = edge_index;
    const int* edst = edge_index + NE;

    const size_t bufelems = (size_t)Nn * E_DIM;               // bf16 elements
    const size_t bufbytes = bufelems * sizeof(unsigned short);

    auto al = [](size_t x) { return (x + 255) & ~(size_t)255; };
    const size_t htBytes  = al(R_REL * bufbytes);             // 9 buffers
    const size_t wtBytes  = al((size_t)2 * R_REL * E_DIM * E_DIM * 2);
    const size_t offBytes = al((size_t)2 * Nn * 4);
    const size_t curBytes = al((size_t)2 * Nn * 4);
    const size_t recBytes = al((size_t)2 * NE * 4);
    const size_t need = htBytes + wtBytes + offBytes + curBytes + recBytes;

    if (ws_size >= need) {
        char* p = (char*)d_ws;
        unsigned short* htB = (unsigned short*)p;        p += htBytes;
        unsigned short* Wt  = (unsigned short*)p;        p += wtBytes;
        int* off            = (int*)p;                   p += offBytes;
        int* cursor         = (int*)p;                   p += curBytes;
        unsigned* rec       = (unsigned*)p;

        hipMemsetAsync(off, 0, (size_t)2 * Nn * 4, stream);
        k_count<<<(NE + 255) / 256, 256, 0, stream>>>(esrc, edst, off, NE, Nn);
        k_scan<<<1, 1024, 0, stream>>>(off, cursor, 2 * Nn);
        k_fill<<<(NE + 255) / 256, 256, 0, stream>>>(esrc, edst, edge_type,
                                                     cursor, rec, NE, Nn);
        w_swizzle<<<2 * R_REL, 256, 0, stream>>>(W2, Wt);

        const int ggrid = (Nn + GBM - 1) / GBM;
        // Pass 0: forward relations 0..8, segments [0, Nn), out = sum.
        gemm_all9<<<ggrid, 256, 0, stream>>>(emb, Wt, B2, htB, Nn, 0);
        k_gather<<<(Nn + 3) / 4, 256, 0, stream>>>(off, cursor, rec, htB, out,
                                                   Nn, 0, 0);
        // Pass 1: backward relations 9..17, segments [Nn, 2Nn), out += sum.
        gemm_all9<<<ggrid, 256, 0, stream>>>(emb, Wt, B2, htB, Nn, R_REL);
        k_gather<<<(Nn + 3) / 4, 256, 0, stream>>>(off, cursor, rec, htB, out,
                                                   Nn, Nn, 1);
        return;
    }

    // Fallbacks (round-2 behavior).
    hipMemsetAsync(d_out, 0, (size_t)Nn * E_DIM * sizeof(float), stream);
    const int nbuf = (int)(ws_size / bufbytes);
    if (nbuf >= 2) {
        const int PG = (nbuf / 2 < R_REL) ? (nbuf / 2) : R_REL;
        unsigned short* htB = (unsigned short*)d_ws;
        const int gx = (Nn + GBM * 4 - 1) / (GBM * 4);
        for (int p0 = 0; p0 < R_REL; ) {
            int pg = (R_REL - p0 < PG) ? (R_REL - p0) : PG;
            dim3 g1(gx, 2 * pg);
            gemm_bf16<<<g1, 256, 0, stream>>>(emb, W2, B2, htB, bufelems, p0, Nn);
            scatter_grp<<<(NE + 3) / 4, 256, 0, stream>>>(
                esrc, edst, edge_type, htB, bufelems, out, NE, p0, pg);
            p0 += pg;
        }
    } else {
        direct_edge<<<NE, 128, 0, stream>>>(esrc, edst, edge_type, emb, W2, B2, out, NE);
    }
}

// Round 5
// 485.721 us; speedup vs baseline: 2.6409x; 1.9026x over previous
//
#include <hip/hip_runtime.h>
#include <hip/hip_bf16.h>

// RGCN encoder: N=100000, E=128, R=9, L=3, NE=640000. Only the LAST layer
// matters (reference resets hidden=embeddings each layer).
//   out[n] = sum_{e:dst=n}(W_t h[src]+b_t) + sum_{e:src=n}(W_{t+9} h[dst]+b_{t+9})
// Fast path (~238 MB ws):
//  (1) w_swizzle: last-layer W -> MFMA B-fragment order, bf16 (0.59 MB, L2-hot)
//  (2) CSR build: per-(node,direction) record lists; hierarchical 3-kernel scan
//      (round-4's single-block k_scan was 456us = half the total runtime)
//  (3) two passes (fwd rels 0..8, bwd rels 9..17):
//      gemm_all9: per 64-row tile stage A once, 9 relations of MFMA, bias
//                 folded, bf16 ht[9][Nn][128] (230.4 MB)
//      k_gather:  one wave per node sums its ht rows, writes out once
//                 (pass 1 accumulates) -- no atomics, no write amplification.

#define E_DIM 128
#define R_REL 9
#define GBM 64
#define SCB 1024   // elements per scan block

typedef __attribute__((ext_vector_type(8))) short short8v;
typedef __attribute__((ext_vector_type(4))) float f32x4;

static __device__ __forceinline__ unsigned short f2bf(float f) {
    union { float f; unsigned u; } v; v.f = f;
    unsigned u = v.u;
    return (unsigned short)((u + 0x7FFFu + ((u >> 16) & 1u)) >> 16);
}
static __device__ __forceinline__ float bf2f(unsigned short h) {
    union { unsigned u; float f; } v; v.u = ((unsigned)h) << 16;
    return v.f;
}

// ---------- fast path ----------

// Wt[rel][w][s][c][lane][j] = bf16(W[rel][k=s*32+(lane>>4)*8+j][col=w*32+c*16+(lane&15)])
__global__ __launch_bounds__(256) void w_swizzle(
    const float* __restrict__ W18, unsigned short* __restrict__ Wt)
{
    const int rel = blockIdx.x;
    const float* __restrict__ Wr = W18 + (size_t)rel * E_DIM * E_DIM;
    const int tid = threadIdx.x;
#pragma unroll
    for (int k = 0; k < 8; k++) {
        int f = tid + k * 256;            // 0..2047
        int lane = f & 63;
        int c = (f >> 6) & 1;
        int s = (f >> 7) & 3;
        int w = (f >> 9) & 3;
        int col = w * 32 + c * 16 + (lane & 15);
        int kb = s * 32 + (lane >> 4) * 8;
        short8v v;
#pragma unroll
        for (int j = 0; j < 8; j++)
            v[j] = (short)f2bf(Wr[(size_t)(kb + j) * E_DIM + col]);
        *(short8v*)(Wt + ((size_t)((((rel * 4 + w) * 4 + s) * 2 + c) * 64 + lane)) * 8) = v;
    }
}

// One block per 64-row tile; stage A once (fp32->bf16), then 9 relations
// rbase..rbase+8 -> buffers q=0..8. No cross-wave barriers in the rel loop.
__global__ __launch_bounds__(256) void gemm_all9(
    const float* __restrict__ H, const unsigned short* __restrict__ Wt,
    const float* __restrict__ B18, unsigned short* __restrict__ htB,
    int Nn, int rbase)
{
    __shared__ __align__(16) unsigned short As[GBM][136];
    __shared__ __align__(16) unsigned short Cs[4][GBM][36];

    const int tid = threadIdx.x;
    const int lane = tid & 63;
    const int w = tid >> 6;
    const int lr = lane & 15;
    const int lg = lane >> 4;
    const int n0 = blockIdx.x * GBM;

#pragma unroll
    for (int j = 0; j < 8; j++) {
        int i = tid + j * 256;
        int row = i >> 5;
        int c4 = (i & 31) * 4;
        int n = n0 + row;
        float4 v = make_float4(0.f, 0.f, 0.f, 0.f);
        if (n < Nn) v = *(const float4*)(H + (size_t)n * E_DIM + c4);
        ushort4 b4;
        b4.x = f2bf(v.x); b4.y = f2bf(v.y); b4.z = f2bf(v.z); b4.w = f2bf(v.w);
        *(ushort4*)(&As[row][c4]) = b4;
    }
    __syncthreads();

    const short8v* wt8 = (const short8v*)Wt;

#pragma unroll 1
    for (int q = 0; q < R_REL; q++) {
        const int rel = rbase + q;
        short8v bfrag[4][2];
#pragma unroll
        for (int s = 0; s < 4; s++)
#pragma unroll
            for (int c = 0; c < 2; c++)
                bfrag[s][c] = wt8[(size_t)((((rel * 4 + w) * 4 + s) * 2 + c) * 64) + lane];

        float bias0 = B18[(size_t)rel * E_DIM + w * 32 + lr];
        float bias1 = B18[(size_t)rel * E_DIM + w * 32 + 16 + lr];

        f32x4 acc[4][2];
#pragma unroll
        for (int m = 0; m < 4; m++)
#pragma unroll
            for (int c = 0; c < 2; c++) acc[m][c] = (f32x4){0.f, 0.f, 0.f, 0.f};

#pragma unroll
        for (int s = 0; s < 4; s++)
#pragma unroll
            for (int m = 0; m < 4; m++) {
                short8v a = *(const short8v*)(&As[m * 16 + lr][s * 32 + lg * 8]);
#pragma unroll
                for (int c = 0; c < 2; c++)
                    acc[m][c] = __builtin_amdgcn_mfma_f32_16x16x32_bf16(
                        a, bfrag[s][c], acc[m][c], 0, 0, 0);
            }

        // Frags (+bias) -> wave-private LDS. D layout: col=lane&15, row=lg*4+p.
#pragma unroll
        for (int m = 0; m < 4; m++)
#pragma unroll
            for (int c = 0; c < 2; c++) {
                float bias = c ? bias1 : bias0;
#pragma unroll
                for (int p = 0; p < 4; p++)
                    Cs[w][m * 16 + lg * 4 + p][c * 16 + lr] = f2bf(acc[m][c][p] + bias);
            }

        unsigned short* ho = htB + ((size_t)q * Nn) * E_DIM;
#pragma unroll
        for (int j = 0; j < 4; j++) {
            int row = (lane >> 2) + j * 16;
            int ch = (lane & 3) * 8;
            int n = n0 + row;
            if (n < Nn) {
                short8v v = *(const short8v*)(&Cs[w][row][ch]);
                *(short8v*)(ho + (size_t)n * E_DIM + w * 32 + ch) = v;
            }
        }
    }
}

// CSR build over 2*Nn segments: seg n = fwd msgs into n (dst), seg Nn+n = bwd (src).
__global__ __launch_bounds__(256) void k_count(
    const int* __restrict__ esrc, const int* __restrict__ edst,
    int* __restrict__ cnt, int ne, int Nn)
{
    int e = blockIdx.x * 256 + threadIdx.x;
    if (e >= ne) return;
    atomicAdd(&cnt[edst[e]], 1);
    atomicAdd(&cnt[Nn + esrc[e]], 1);
}

// Hierarchical scan, 3 kernels. part: per-block local exclusive prefix -> loc,
// block totals -> bsum. mid: exclusive-scan bsum (single small block, chunked).
// apply: off/cursor = loc + bsum[block].
__global__ __launch_bounds__(256) void k_scan_part(
    const int* __restrict__ cnt, int* __restrict__ loc,
    int* __restrict__ bsum, int n2)
{
    __shared__ int sh[256];
    const int tid = threadIdx.x;
    const int i0 = blockIdx.x * SCB + tid * 4;
    int v0 = 0, v1 = 0, v2 = 0, v3 = 0;
    if (i0 + 3 < n2) {
        int4 v = *(const int4*)(cnt + i0);
        v0 = v.x; v1 = v.y; v2 = v.z; v3 = v.w;
    } else {
        if (i0 + 0 < n2) v0 = cnt[i0 + 0];
        if (i0 + 1 < n2) v1 = cnt[i0 + 1];
        if (i0 + 2 < n2) v2 = cnt[i0 + 2];
        if (i0 + 3 < n2) v3 = cnt[i0 + 3];
    }
    int t = v0 + v1 + v2 + v3;
    sh[tid] = t;
    __syncthreads();
    for (int o = 1; o < 256; o <<= 1) {
        int x = (tid >= o) ? sh[tid - o] : 0;
        __syncthreads();
        sh[tid] += x;
        __syncthreads();
    }
    int excl = sh[tid] - t;
    if (tid == 255) bsum[blockIdx.x] = sh[255];
    int p0 = excl, p1 = p0 + v0, p2 = p1 + v1, p3 = p2 + v2;
    if (i0 + 3 < n2) {
        *(int4*)(loc + i0) = make_int4(p0, p1, p2, p3);
    } else {
        if (i0 + 0 < n2) loc[i0 + 0] = p0;
        if (i0 + 1 < n2) loc[i0 + 1] = p1;
        if (i0 + 2 < n2) loc[i0 + 2] = p2;
        if (i0 + 3 < n2) loc[i0 + 3] = p3;
    }
}

__global__ __launch_bounds__(256) void k_scan_mid(int* __restrict__ bsum, int nb)
{
    __shared__ int sh[256];
    __shared__ int carry;
    const int tid = threadIdx.x;
    if (tid == 0) carry = 0;
    __syncthreads();
    for (int base = 0; base < nb; base += 256) {
        int i = base + tid;
        int v = (i < nb) ? bsum[i] : 0;
        sh[tid] = v;
        __syncthreads();
        for (int o = 1; o < 256; o <<= 1) {
            int x = (tid >= o) ? sh[tid - o] : 0;
            __syncthreads();
            sh[tid] += x;
            __syncthreads();
        }
        int excl = sh[tid] - v + carry;
        int total = sh[255];
        if (i < nb) bsum[i] = excl;
        __syncthreads();
        if (tid == 0) carry += total;
        __syncthreads();
    }
}

__global__ __launch_bounds__(256) void k_scan_apply(
    const int* __restrict__ loc, const int* __restrict__ bsum,
    int* __restrict__ off, int* __restrict__ cursor, int n2)
{
    const int add = bsum[blockIdx.x];
    const int i0 = blockIdx.x * SCB + threadIdx.x * 4;
    if (i0 + 3 < n2) {
        int4 v = *(const int4*)(loc + i0);
        v.x += add; v.y += add; v.z += add; v.w += add;
        *(int4*)(off + i0) = v;
        *(int4*)(cursor + i0) = v;
    } else {
#pragma unroll
        for (int j = 0; j < 4; j++)
            if (i0 + j < n2) {
                int v = loc[i0 + j] + add;
                off[i0 + j] = v;
                cursor[i0 + j] = v;
            }
    }
}

// rec value = relInGroup*Nn + otherNode (relInGroup = edge_type, both groups).
__global__ __launch_bounds__(256) void k_fill(
    const int* __restrict__ esrc, const int* __restrict__ edst,
    const int* __restrict__ etype, int* __restrict__ cursor,
    unsigned* __restrict__ rec, int ne, int Nn)
{
    int e = blockIdx.x * 256 + threadIdx.x;
    if (e >= ne) return;
    int t = etype[e], s = esrc[e], d = edst[e];
    int p = atomicAdd(&cursor[d], 1);
    rec[p] = (unsigned)(t * Nn + s);        // fwd: rel t (buffer t, pass 0)
    int p2 = atomicAdd(&cursor[Nn + s], 1);
    rec[p2] = (unsigned)(t * Nn + d);       // bwd: rel t+9 (buffer t, pass 1)
}

// One wave per node: sum bias-folded ht rows of segment base+wid; write once.
__global__ __launch_bounds__(256) void k_gather(
    const int* __restrict__ off, const int* __restrict__ cur,
    const unsigned* __restrict__ rec, const unsigned short* __restrict__ htB,
    float* __restrict__ out, int Nn, int base, int accum)
{
    int wid = blockIdx.x * 4 + (threadIdx.x >> 6);
    if (wid >= Nn) return;
    int lane = threadIdx.x & 63;
    int i = off[base + wid], end = cur[base + wid];
    const ushort2* h2 = (const ushort2*)htB;
    float ax = 0.f, ay = 0.f;
    if (accum) {
        float2 prev = *(const float2*)(out + (size_t)wid * E_DIM + 2 * lane);
        ax = prev.x; ay = prev.y;
    }
    for (; i + 2 <= end; i += 2) {
        unsigned r0 = rec[i], r1 = rec[i + 1];
        ushort2 v0 = h2[(size_t)r0 * 64 + lane];
        ushort2 v1 = h2[(size_t)r1 * 64 + lane];
        ax += bf2f(v0.x) + bf2f(v1.x);
        ay += bf2f(v0.y) + bf2f(v1.y);
    }
    if (i < end) {
        ushort2 v = h2[(size_t)rec[i] * 64 + lane];
        ax += bf2f(v.x);
        ay += bf2f(v.y);
    }
    *(float2*)(out + (size_t)wid * E_DIM + 2 * lane) = make_float2(ax, ay);
}

// ---------- fallback path (round-2, validated) ----------

__global__ __launch_bounds__(256) void gemm_bf16(
    const float* __restrict__ H, const float* __restrict__ W18,
    const float* __restrict__ B18, unsigned short* __restrict__ htB,
    size_t bufstride, int p0, int Nn)
{
    __shared__ __align__(16) unsigned short As[GBM][136];

    const int b = blockIdx.y;
    const int rel = p0 + (b >> 1) + ((b & 1) ? R_REL : 0);
    const float* __restrict__ Wr = W18 + (size_t)rel * E_DIM * E_DIM;
    unsigned short* __restrict__ ho = htB + (size_t)b * bufstride;

    const int tid = threadIdx.x;
    const int lane = tid & 63;
    const int wc = (tid >> 6) * 32;
    const int lr = lane & 15;
    const int lg = lane >> 4;

    short8v bfrag[4][2];
#pragma unroll
    for (int s = 0; s < 4; s++)
#pragma unroll
        for (int c = 0; c < 2; c++) {
#pragma unroll
            for (int j = 0; j < 8; j++) {
                float wv = Wr[(size_t)(s * 32 + lg * 8 + j) * E_DIM + wc + c * 16 + lr];
                bfrag[s][c][j] = (short)f2bf(wv);
            }
        }
    const float bias0 = B18[(size_t)rel * E_DIM + wc + lr];
    const float bias1 = B18[(size_t)rel * E_DIM + wc + 16 + lr];

    const int ntiles = (Nn + GBM - 1) / GBM;
    for (int rt = blockIdx.x; rt < ntiles; rt += gridDim.x) {
        const int n0 = rt * GBM;
#pragma unroll
        for (int j = 0; j < 8; j++) {
            int i = tid + j * 256;
            int row = i >> 5;
            int c4 = (i & 31) * 4;
            int n = n0 + row;
            float4 v = make_float4(0.f, 0.f, 0.f, 0.f);
            if (n < Nn) v = *(const float4*)(H + (size_t)n * E_DIM + c4);
            ushort4 b4;
            b4.x = f2bf(v.x); b4.y = f2bf(v.y); b4.z = f2bf(v.z); b4.w = f2bf(v.w);
            *(ushort4*)(&As[row][c4]) = b4;
        }
        __syncthreads();

        f32x4 acc[4][2];
#pragma unroll
        for (int m = 0; m < 4; m++)
#pragma unroll
            for (int c = 0; c < 2; c++) acc[m][c] = (f32x4){0.f, 0.f, 0.f, 0.f};

#pragma unroll
        for (int s = 0; s < 4; s++)
#pragma unroll
            for (int m = 0; m < 4; m++) {
                short8v a = *(const short8v*)(&As[m * 16 + lr][s * 32 + lg * 8]);
#pragma unroll
                for (int c = 0; c < 2; c++)
                    acc[m][c] = __builtin_amdgcn_mfma_f32_16x16x32_bf16(
                        a, bfrag[s][c], acc[m][c], 0, 0, 0);
            }
        __syncthreads();

#pragma unroll
        for (int m = 0; m < 4; m++)
#pragma unroll
            for (int c = 0; c < 2; c++) {
                float bias = c ? bias1 : bias0;
#pragma unroll
                for (int p = 0; p < 4; p++)
                    As[m * 16 + lg * 4 + p][wc + c * 16 + lr] = f2bf(acc[m][c][p] + bias);
            }
        __syncthreads();

#pragma unroll
        for (int j = 0; j < 4; j++) {
            int i = tid + j * 256;
            int row = i >> 4;
            int c8 = (i & 15) * 8;
            int n = n0 + row;
            if (n < Nn) {
                short8v v = *(const short8v*)(&As[row][c8]);
                *(short8v*)(ho + (size_t)n * E_DIM + c8) = v;
            }
        }
        __syncthreads();
    }
}

__global__ __launch_bounds__(256) void scatter_grp(
    const int* __restrict__ esrc, const int* __restrict__ edst,
    const int* __restrict__ etype,
    const unsigned short* __restrict__ htB, size_t bufstride,
    float* __restrict__ out, int ne, int p0, int pg)
{
    int wid = blockIdx.x * 4 + (threadIdx.x >> 6);
    if (wid >= ne) return;
    int t = etype[wid];
    int q = t - p0;
    if ((unsigned)q >= (unsigned)pg) return;
    int lane = threadIdx.x & 63;
    int s = esrc[wid], d = edst[wid];

    const ushort2* vf = (const ushort2*)(htB + (size_t)(2 * q) * bufstride + (size_t)s * E_DIM);
    const ushort2* vb = (const ushort2*)(htB + (size_t)(2 * q + 1) * bufstride + (size_t)d * E_DIM);
    ushort2 a = vf[lane];
    ushort2 c = vb[lane];

    float* od = out + (size_t)d * E_DIM + 2 * lane;
    float* os = out + (size_t)s * E_DIM + 2 * lane;
    atomicAdd(od + 0, bf2f(a.x));
    atomicAdd(od + 1, bf2f(a.y));
    atomicAdd(os + 0, bf2f(c.x));
    atomicAdd(os + 1, bf2f(c.y));
}

__global__ __launch_bounds__(128) void direct_edge(
    const int* __restrict__ esrc, const int* __restrict__ edst,
    const int* __restrict__ etype,
    const float* __restrict__ H, const float* __restrict__ W2,
    const float* __restrict__ B2, float* __restrict__ out, int ne)
{
    __shared__ float hs[E_DIM];
    __shared__ float hd[E_DIM];
    int e = blockIdx.x;
    if (e >= ne) return;
    int t = etype[e], s = esrc[e], d = edst[e];
    int c = threadIdx.x;
    hs[c] = H[(size_t)s * E_DIM + c];
    hd[c] = H[(size_t)d * E_DIM + c];
    __syncthreads();
    const float* Wf = W2 + (size_t)t * E_DIM * E_DIM;
    const float* Wb = W2 + (size_t)(t + R_REL) * E_DIM * E_DIM;
    float accf = B2[(size_t)t * E_DIM + c];
    float accb = B2[(size_t)(t + R_REL) * E_DIM + c];
#pragma unroll 8
    for (int k = 0; k < E_DIM; k++) {
        accf += hs[k] * Wf[(size_t)k * E_DIM + c];
        accb += hd[k] * Wb[(size_t)k * E_DIM + c];
    }
    atomicAdd(&out[(size_t)d * E_DIM + c], accf);
    atomicAdd(&out[(size_t)s * E_DIM + c], accb);
}

extern "C" void kernel_launch(void* const* d_in, const int* in_sizes, int n_in,
                              void* d_out, int out_size, void* d_ws, size_t ws_size,
                              hipStream_t stream) {
    const int* edge_index = (const int*)d_in[0];   // [2][NE]
    const int* edge_type  = (const int*)d_in[1];   // [NE]
    const float* emb      = (const float*)d_in[2]; // [N][128]
    const float* weights  = (const float*)d_in[3]; // [L][18][128][128]
    const float* biases   = (const float*)d_in[4]; // [L][18][128]
    float* out = (float*)d_out;

    const int NE = in_sizes[1];
    const int Nn = in_sizes[2] / E_DIM;
    const int L  = in_sizes[3] / (2 * R_REL * E_DIM * E_DIM);

    const float* W2 = weights + (size_t)(L - 1) * 2 * R_REL * E_DIM * E_DIM;
    const float* B2 = biases  + (size_t)(L - 1) * 2 * R_REL * E_DIM;

    const int* esrc = edge_index;
    const int* edst = edge_index + NE;

    const size_t bufelems = (size_t)Nn * E_DIM;               // bf16 elements
    const size_t bufbytes = bufelems * sizeof(unsigned short);
    const int n2 = 2 * Nn;
    const int nb = (n2 + SCB - 1) / SCB;

    auto al = [](size_t x) { return (x + 255) & ~(size_t)255; };
    const size_t htBytes  = al(R_REL * bufbytes);             // 9 buffers
    const size_t wtBytes  = al((size_t)2 * R_REL * E_DIM * E_DIM * 2);
    const size_t offBytes = al((size_t)n2 * 4);
    const size_t curBytes = al((size_t)n2 * 4);
    const size_t recBytes = al((size_t)2 * NE * 4);
    const size_t bsBytes  = al((size_t)nb * 4);
    const size_t need = htBytes + wtBytes + offBytes + curBytes + recBytes + bsBytes;

    if (ws_size >= need) {
        char* p = (char*)d_ws;
        unsigned short* htB = (unsigned short*)p;        p += htBytes;
        unsigned short* Wt  = (unsigned short*)p;        p += wtBytes;
        int* off            = (int*)p;                   p += offBytes;
        int* cursor         = (int*)p;                   p += curBytes;
        unsigned* rec       = (unsigned*)p;              p += recBytes;
        int* bsum           = (int*)p;

        hipMemsetAsync(off, 0, (size_t)n2 * 4, stream);
        k_count<<<(NE + 255) / 256, 256, 0, stream>>>(esrc, edst, off, NE, Nn);
        // Hierarchical scan: off(counts) -> off/cursor(exclusive prefixes).
        k_scan_part<<<nb, 256, 0, stream>>>(off, cursor, bsum, n2);
        k_scan_mid<<<1, 256, 0, stream>>>(bsum, nb);
        k_scan_apply<<<nb, 256, 0, stream>>>(cursor, bsum, off, cursor, n2);
        k_fill<<<(NE + 255) / 256, 256, 0, stream>>>(esrc, edst, edge_type,
                                                     cursor, rec, NE, Nn);
        w_swizzle<<<2 * R_REL, 256, 0, stream>>>(W2, Wt);

        const int ggrid = (Nn + GBM - 1) / GBM;
        // Pass 0: forward relations 0..8, segments [0, Nn), out = sum.
        gemm_all9<<<ggrid, 256, 0, stream>>>(emb, Wt, B2, htB, Nn, 0);
        k_gather<<<(Nn + 3) / 4, 256, 0, stream>>>(off, cursor, rec, htB, out,
                                                   Nn, 0, 0);
        // Pass 1: backward relations 9..17, segments [Nn, 2Nn), out += sum.
        gemm_all9<<<ggrid, 256, 0, stream>>>(emb, Wt, B2, htB, Nn, R_REL);
        k_gather<<<(Nn + 3) / 4, 256, 0, stream>>>(off, cursor, rec, htB, out,
                                                   Nn, Nn, 1);
        return;
    }

    // Fallbacks (round-2 behavior).
    hipMemsetAsync(d_out, 0, (size_t)Nn * E_DIM * sizeof(float), stream);
    const int nbuf = (int)(ws_size / bufbytes);
    if (nbuf >= 2) {
        const int PG = (nbuf / 2 < R_REL) ? (nbuf / 2) : R_REL;
        unsigned short* htB = (unsigned short*)d_ws;
        const int gx = (Nn + GBM * 4 - 1) / (GBM * 4);
        for (int p0 = 0; p0 < R_REL; ) {
            int pg = (R_REL - p0 < PG) ? (R_REL - p0) : PG;
            dim3 g1(gx, 2 * pg);
            gemm_bf16<<<g1, 256, 0, stream>>>(emb, W2, B2, htB, bufelems, p0, Nn);
            scatter_grp<<<(NE + 3) / 4, 256, 0, stream>>>(
                esrc, edst, edge_type, htB, bufelems, out, NE, p0, pg);
            p0 += pg;
        }
    } else {
        direct_edge<<<NE, 128, 0, stream>>>(esrc, edst, edge_type, emb, W2, B2, out, NE);
    }
}

// Round 6
// 436.883 us; speedup vs baseline: 2.9361x; 1.1118x over previous
//
#include <hip/hip_runtime.h>
#include <hip/hip_bf16.h>

// RGCN encoder: N=100000, E=128, R=9, L=3, NE=640000. Only the LAST layer
// matters (reference resets hidden=embeddings each layer).
//   out[n] = sum_{e:dst=n}(W_t h[src]+b_t) + sum_{e:src=n}(W_{t+9} h[dst]+b_{t+9})
// Fast path (~238 MB ws):
//  (1) w_swizzle: last-layer W -> MFMA B-fragment order, bf16 (L2-hot)
//  (2) CSR build: octant-partitioned count/fill (blockIdx&7 -> node octant;
//      each octant's cursor/rec window ~1.3MB stays in ONE XCD's L2 --
//      round-5 k_fill wrote 90MB of HBM for a 5MB rec array, 17x ampl.)
//      + hierarchical 3-kernel scan
//  (3) two passes (fwd rels 0..8, bwd rels 9..17):
//      gemm_all9: per 64-row tile stage A once, 9 relations of MFMA, bias
//                 folded, bf16 ht[9][Nn][128] (230.4 MB)
//      k_gather:  one wave per node sums its ht rows (4-deep unroll),
//                 writes out once -- no atomics, no write amplification.

#define E_DIM 128
#define R_REL 9
#define GBM 64
#define SCB 1024   // elements per scan block
#define NSLICE 96  // edge slices per octant in count/fill

typedef __attribute__((ext_vector_type(8))) short short8v;
typedef __attribute__((ext_vector_type(4))) float f32x4;

static __device__ __forceinline__ unsigned short f2bf(float f) {
    union { float f; unsigned u; } v; v.f = f;
    unsigned u = v.u;
    return (unsigned short)((u + 0x7FFFu + ((u >> 16) & 1u)) >> 16);
}
static __device__ __forceinline__ float bf2f(unsigned short h) {
    union { unsigned u; float f; } v; v.u = ((unsigned)h) << 16;
    return v.f;
}

// ---------- fast path ----------

// Wt[rel][w][s][c][lane][j] = bf16(W[rel][k=s*32+(lane>>4)*8+j][col=w*32+c*16+(lane&15)])
__global__ __launch_bounds__(256) void w_swizzle(
    const float* __restrict__ W18, unsigned short* __restrict__ Wt)
{
    const int rel = blockIdx.x;
    const float* __restrict__ Wr = W18 + (size_t)rel * E_DIM * E_DIM;
    const int tid = threadIdx.x;
#pragma unroll
    for (int k = 0; k < 8; k++) {
        int f = tid + k * 256;            // 0..2047
        int lane = f & 63;
        int c = (f >> 6) & 1;
        int s = (f >> 7) & 3;
        int w = (f >> 9) & 3;
        int col = w * 32 + c * 16 + (lane & 15);
        int kb = s * 32 + (lane >> 4) * 8;
        short8v v;
#pragma unroll
        for (int j = 0; j < 8; j++)
            v[j] = (short)f2bf(Wr[(size_t)(kb + j) * E_DIM + col]);
        *(short8v*)(Wt + ((size_t)((((rel * 4 + w) * 4 + s) * 2 + c) * 64 + lane)) * 8) = v;
    }
}

// One block per 64-row tile; stage A once (fp32->bf16), then 9 relations
// rbase..rbase+8 -> buffers q=0..8. No cross-wave barriers in the rel loop.
__global__ __launch_bounds__(256) void gemm_all9(
    const float* __restrict__ H, const unsigned short* __restrict__ Wt,
    const float* __restrict__ B18, unsigned short* __restrict__ htB,
    int Nn, int rbase)
{
    __shared__ __align__(16) unsigned short As[GBM][136];
    __shared__ __align__(16) unsigned short Cs[4][GBM][36];

    const int tid = threadIdx.x;
    const int lane = tid & 63;
    const int w = tid >> 6;
    const int lr = lane & 15;
    const int lg = lane >> 4;
    const int n0 = blockIdx.x * GBM;

#pragma unroll
    for (int j = 0; j < 8; j++) {
        int i = tid + j * 256;
        int row = i >> 5;
        int c4 = (i & 31) * 4;
        int n = n0 + row;
        float4 v = make_float4(0.f, 0.f, 0.f, 0.f);
        if (n < Nn) v = *(const float4*)(H + (size_t)n * E_DIM + c4);
        ushort4 b4;
        b4.x = f2bf(v.x); b4.y = f2bf(v.y); b4.z = f2bf(v.z); b4.w = f2bf(v.w);
        *(ushort4*)(&As[row][c4]) = b4;
    }
    __syncthreads();

    const short8v* wt8 = (const short8v*)Wt;

#pragma unroll 1
    for (int q = 0; q < R_REL; q++) {
        const int rel = rbase + q;
        short8v bfrag[4][2];
#pragma unroll
        for (int s = 0; s < 4; s++)
#pragma unroll
            for (int c = 0; c < 2; c++)
                bfrag[s][c] = wt8[(size_t)((((rel * 4 + w) * 4 + s) * 2 + c) * 64) + lane];

        float bias0 = B18[(size_t)rel * E_DIM + w * 32 + lr];
        float bias1 = B18[(size_t)rel * E_DIM + w * 32 + 16 + lr];

        f32x4 acc[4][2];
#pragma unroll
        for (int m = 0; m < 4; m++)
#pragma unroll
            for (int c = 0; c < 2; c++) acc[m][c] = (f32x4){0.f, 0.f, 0.f, 0.f};

#pragma unroll
        for (int s = 0; s < 4; s++)
#pragma unroll
            for (int m = 0; m < 4; m++) {
                short8v a = *(const short8v*)(&As[m * 16 + lr][s * 32 + lg * 8]);
#pragma unroll
                for (int c = 0; c < 2; c++)
                    acc[m][c] = __builtin_amdgcn_mfma_f32_16x16x32_bf16(
                        a, bfrag[s][c], acc[m][c], 0, 0, 0);
            }

        // Frags (+bias) -> wave-private LDS. D layout: col=lane&15, row=lg*4+p.
#pragma unroll
        for (int m = 0; m < 4; m++)
#pragma unroll
            for (int c = 0; c < 2; c++) {
                float bias = c ? bias1 : bias0;
#pragma unroll
                for (int p = 0; p < 4; p++)
                    Cs[w][m * 16 + lg * 4 + p][c * 16 + lr] = f2bf(acc[m][c][p] + bias);
            }

        unsigned short* ho = htB + ((size_t)q * Nn) * E_DIM;
#pragma unroll
        for (int j = 0; j < 4; j++) {
            int row = (lane >> 2) + j * 16;
            int ch = (lane & 3) * 8;
            int n = n0 + row;
            if (n < Nn) {
                short8v v = *(const short8v*)(&Cs[w][row][ch]);
                *(short8v*)(ho + (size_t)n * E_DIM + w * 32 + ch) = v;
            }
        }
    }
}

// CSR build over 2*Nn segments: seg n = fwd msgs into n (dst), seg Nn+n = bwd (src).
// Octant-partitioned: blockIdx&7 selects node octant (in practice = XCD id on
// CDNA round-robin dispatch) so counter/rec windows are XCD-L2-local.
__global__ __launch_bounds__(256) void k_count8(
    const int* __restrict__ esrc, const int* __restrict__ edst,
    int* __restrict__ cnt, int ne, int Nn)
{
    const int oct = blockIdx.x & 7;
    const int slice = blockIdx.x >> 3;
    const int lo = (int)(((long long)oct * Nn) >> 3);
    const int hi = (int)(((long long)(oct + 1) * Nn) >> 3);
    for (int e = slice * 256 + threadIdx.x; e < ne; e += NSLICE * 256) {
        int s = esrc[e], d = edst[e];
        if (d >= lo && d < hi) atomicAdd(&cnt[d], 1);
        if (s >= lo && s < hi) atomicAdd(&cnt[Nn + s], 1);
    }
}

// Hierarchical scan, 3 kernels.
__global__ __launch_bounds__(256) void k_scan_part(
    const int* __restrict__ cnt, int* __restrict__ loc,
    int* __restrict__ bsum, int n2)
{
    __shared__ int sh[256];
    const int tid = threadIdx.x;
    const int i0 = blockIdx.x * SCB + tid * 4;
    int v0 = 0, v1 = 0, v2 = 0, v3 = 0;
    if (i0 + 3 < n2) {
        int4 v = *(const int4*)(cnt + i0);
        v0 = v.x; v1 = v.y; v2 = v.z; v3 = v.w;
    } else {
        if (i0 + 0 < n2) v0 = cnt[i0 + 0];
        if (i0 + 1 < n2) v1 = cnt[i0 + 1];
        if (i0 + 2 < n2) v2 = cnt[i0 + 2];
        if (i0 + 3 < n2) v3 = cnt[i0 + 3];
    }
    int t = v0 + v1 + v2 + v3;
    sh[tid] = t;
    __syncthreads();
    for (int o = 1; o < 256; o <<= 1) {
        int x = (tid >= o) ? sh[tid - o] : 0;
        __syncthreads();
        sh[tid] += x;
        __syncthreads();
    }
    int excl = sh[tid] - t;
    if (tid == 255) bsum[blockIdx.x] = sh[255];
    int p0 = excl, p1 = p0 + v0, p2 = p1 + v1, p3 = p2 + v2;
    if (i0 + 3 < n2) {
        *(int4*)(loc + i0) = make_int4(p0, p1, p2, p3);
    } else {
        if (i0 + 0 < n2) loc[i0 + 0] = p0;
        if (i0 + 1 < n2) loc[i0 + 1] = p1;
        if (i0 + 2 < n2) loc[i0 + 2] = p2;
        if (i0 + 3 < n2) loc[i0 + 3] = p3;
    }
}

__global__ __launch_bounds__(256) void k_scan_mid(int* __restrict__ bsum, int nb)
{
    __shared__ int sh[256];
    __shared__ int carry;
    const int tid = threadIdx.x;
    if (tid == 0) carry = 0;
    __syncthreads();
    for (int base = 0; base < nb; base += 256) {
        int i = base + tid;
        int v = (i < nb) ? bsum[i] : 0;
        sh[tid] = v;
        __syncthreads();
        for (int o = 1; o < 256; o <<= 1) {
            int x = (tid >= o) ? sh[tid - o] : 0;
            __syncthreads();
            sh[tid] += x;
            __syncthreads();
        }
        int excl = sh[tid] - v + carry;
        int total = sh[255];
        if (i < nb) bsum[i] = excl;
        __syncthreads();
        if (tid == 0) carry += total;
        __syncthreads();
    }
}

__global__ __launch_bounds__(256) void k_scan_apply(
    const int* __restrict__ loc, const int* __restrict__ bsum,
    int* __restrict__ off, int* __restrict__ cursor, int n2)
{
    const int add = bsum[blockIdx.x];
    const int i0 = blockIdx.x * SCB + threadIdx.x * 4;
    if (i0 + 3 < n2) {
        int4 v = *(const int4*)(loc + i0);
        v.x += add; v.y += add; v.z += add; v.w += add;
        *(int4*)(off + i0) = v;
        *(int4*)(cursor + i0) = v;
    } else {
#pragma unroll
        for (int j = 0; j < 4; j++)
            if (i0 + j < n2) {
                int v = loc[i0 + j] + add;
                off[i0 + j] = v;
                cursor[i0 + j] = v;
            }
    }
}

// rec value = relInGroup*Nn + otherNode. Octant-partitioned like k_count8.
__global__ __launch_bounds__(256) void k_fill8(
    const int* __restrict__ esrc, const int* __restrict__ edst,
    const int* __restrict__ etype, int* __restrict__ cursor,
    unsigned* __restrict__ rec, int ne, int Nn)
{
    const int oct = blockIdx.x & 7;
    const int slice = blockIdx.x >> 3;
    const int lo = (int)(((long long)oct * Nn) >> 3);
    const int hi = (int)(((long long)(oct + 1) * Nn) >> 3);
    for (int e = slice * 256 + threadIdx.x; e < ne; e += NSLICE * 256) {
        int t = etype[e], s = esrc[e], d = edst[e];
        if (d >= lo && d < hi) {
            int p = atomicAdd(&cursor[d], 1);
            rec[p] = (unsigned)(t * Nn + s);        // fwd: rel t (pass 0)
        }
        if (s >= lo && s < hi) {
            int p2 = atomicAdd(&cursor[Nn + s], 1);
            rec[p2] = (unsigned)(t * Nn + d);       // bwd: rel t+9 (pass 1)
        }
    }
}

// One wave per node: sum bias-folded ht rows of segment base+wid; write once.
// 4-deep unroll for latency hiding; rec reads are wave-uniform (scalar).
__global__ __launch_bounds__(256) void k_gather(
    const int* __restrict__ off, const int* __restrict__ cur,
    const unsigned* __restrict__ rec, const unsigned short* __restrict__ htB,
    float* __restrict__ out, int Nn, int base, int accum)
{
    int wid = blockIdx.x * 4 + (threadIdx.x >> 6);
    if (wid >= Nn) return;
    int lane = threadIdx.x & 63;
    int i = off[base + wid], end = cur[base + wid];
    const ushort2* h2 = (const ushort2*)htB;
    float ax = 0.f, ay = 0.f;
    if (accum) {
        float2 prev = *(const float2*)(out + (size_t)wid * E_DIM + 2 * lane);
        ax = prev.x; ay = prev.y;
    }
    for (; i + 4 <= end; i += 4) {
        unsigned r0 = rec[i], r1 = rec[i + 1], r2 = rec[i + 2], r3 = rec[i + 3];
        ushort2 v0 = h2[(size_t)r0 * 64 + lane];
        ushort2 v1 = h2[(size_t)r1 * 64 + lane];
        ushort2 v2 = h2[(size_t)r2 * 64 + lane];
        ushort2 v3 = h2[(size_t)r3 * 64 + lane];
        ax += bf2f(v0.x) + bf2f(v1.x) + bf2f(v2.x) + bf2f(v3.x);
        ay += bf2f(v0.y) + bf2f(v1.y) + bf2f(v2.y) + bf2f(v3.y);
    }
    for (; i < end; i++) {
        ushort2 v = h2[(size_t)rec[i] * 64 + lane];
        ax += bf2f(v.x);
        ay += bf2f(v.y);
    }
    *(float2*)(out + (size_t)wid * E_DIM + 2 * lane) = make_float2(ax, ay);
}

// ---------- fallback path (round-2, validated) ----------

__global__ __launch_bounds__(256) void gemm_bf16(
    const float* __restrict__ H, const float* __restrict__ W18,
    const float* __restrict__ B18, unsigned short* __restrict__ htB,
    size_t bufstride, int p0, int Nn)
{
    __shared__ __align__(16) unsigned short As[GBM][136];

    const int b = blockIdx.y;
    const int rel = p0 + (b >> 1) + ((b & 1) ? R_REL : 0);
    const float* __restrict__ Wr = W18 + (size_t)rel * E_DIM * E_DIM;
    unsigned short* __restrict__ ho = htB + (size_t)b * bufstride;

    const int tid = threadIdx.x;
    const int lane = tid & 63;
    const int wc = (tid >> 6) * 32;
    const int lr = lane & 15;
    const int lg = lane >> 4;

    short8v bfrag[4][2];
#pragma unroll
    for (int s = 0; s < 4; s++)
#pragma unroll
        for (int c = 0; c < 2; c++) {
#pragma unroll
            for (int j = 0; j < 8; j++) {
                float wv = Wr[(size_t)(s * 32 + lg * 8 + j) * E_DIM + wc + c * 16 + lr];
                bfrag[s][c][j] = (short)f2bf(wv);
            }
        }
    const float bias0 = B18[(size_t)rel * E_DIM + wc + lr];
    const float bias1 = B18[(size_t)rel * E_DIM + wc + 16 + lr];

    const int ntiles = (Nn + GBM - 1) / GBM;
    for (int rt = blockIdx.x; rt < ntiles; rt += gridDim.x) {
        const int n0 = rt * GBM;
#pragma unroll
        for (int j = 0; j < 8; j++) {
            int i = tid + j * 256;
            int row = i >> 5;
            int c4 = (i & 31) * 4;
            int n = n0 + row;
            float4 v = make_float4(0.f, 0.f, 0.f, 0.f);
            if (n < Nn) v = *(const float4*)(H + (size_t)n * E_DIM + c4);
            ushort4 b4;
            b4.x = f2bf(v.x); b4.y = f2bf(v.y); b4.z = f2bf(v.z); b4.w = f2bf(v.w);
            *(ushort4*)(&As[row][c4]) = b4;
        }
        __syncthreads();

        f32x4 acc[4][2];
#pragma unroll
        for (int m = 0; m < 4; m++)
#pragma unroll
            for (int c = 0; c < 2; c++) acc[m][c] = (f32x4){0.f, 0.f, 0.f, 0.f};

#pragma unroll
        for (int s = 0; s < 4; s++)
#pragma unroll
            for (int m = 0; m < 4; m++) {
                short8v a = *(const short8v*)(&As[m * 16 + lr][s * 32 + lg * 8]);
#pragma unroll
                for (int c = 0; c < 2; c++)
                    acc[m][c] = __builtin_amdgcn_mfma_f32_16x16x32_bf16(
                        a, bfrag[s][c], acc[m][c], 0, 0, 0);
            }
        __syncthreads();

#pragma unroll
        for (int m = 0; m < 4; m++)
#pragma unroll
            for (int c = 0; c < 2; c++) {
                float bias = c ? bias1 : bias0;
#pragma unroll
                for (int p = 0; p < 4; p++)
                    As[m * 16 + lg * 4 + p][wc + c * 16 + lr] = f2bf(acc[m][c][p] + bias);
            }
        __syncthreads();

#pragma unroll
        for (int j = 0; j < 4; j++) {
            int i = tid + j * 256;
            int row = i >> 4;
            int c8 = (i & 15) * 8;
            int n = n0 + row;
            if (n < Nn) {
                short8v v = *(const short8v*)(&As[row][c8]);
                *(short8v*)(ho + (size_t)n * E_DIM + c8) = v;
            }
        }
        __syncthreads();
    }
}

__global__ __launch_bounds__(256) void scatter_grp(
    const int* __restrict__ esrc, const int* __restrict__ edst,
    const int* __restrict__ etype,
    const unsigned short* __restrict__ htB, size_t bufstride,
    float* __restrict__ out, int ne, int p0, int pg)
{
    int wid = blockIdx.x * 4 + (threadIdx.x >> 6);
    if (wid >= ne) return;
    int t = etype[wid];
    int q = t - p0;
    if ((unsigned)q >= (unsigned)pg) return;
    int lane = threadIdx.x & 63;
    int s = esrc[wid], d = edst[wid];

    const ushort2* vf = (const ushort2*)(htB + (size_t)(2 * q) * bufstride + (size_t)s * E_DIM);
    const ushort2* vb = (const ushort2*)(htB + (size_t)(2 * q + 1) * bufstride + (size_t)d * E_DIM);
    ushort2 a = vf[lane];
    ushort2 c = vb[lane];

    float* od = out + (size_t)d * E_DIM + 2 * lane;
    float* os = out + (size_t)s * E_DIM + 2 * lane;
    atomicAdd(od + 0, bf2f(a.x));
    atomicAdd(od + 1, bf2f(a.y));
    atomicAdd(os + 0, bf2f(c.x));
    atomicAdd(os + 1, bf2f(c.y));
}

__global__ __launch_bounds__(128) void direct_edge(
    const int* __restrict__ esrc, const int* __restrict__ edst,
    const int* __restrict__ etype,
    const float* __restrict__ H, const float* __restrict__ W2,
    const float* __restrict__ B2, float* __restrict__ out, int ne)
{
    __shared__ float hs[E_DIM];
    __shared__ float hd[E_DIM];
    int e = blockIdx.x;
    if (e >= ne) return;
    int t = etype[e], s = esrc[e], d = edst[e];
    int c = threadIdx.x;
    hs[c] = H[(size_t)s * E_DIM + c];
    hd[c] = H[(size_t)d * E_DIM + c];
    __syncthreads();
    const float* Wf = W2 + (size_t)t * E_DIM * E_DIM;
    const float* Wb = W2 + (size_t)(t + R_REL) * E_DIM * E_DIM;
    float accf = B2[(size_t)t * E_DIM + c];
    float accb = B2[(size_t)(t + R_REL) * E_DIM + c];
#pragma unroll 8
    for (int k = 0; k < E_DIM; k++) {
        accf += hs[k] * Wf[(size_t)k * E_DIM + c];
        accb += hd[k] * Wb[(size_t)k * E_DIM + c];
    }
    atomicAdd(&out[(size_t)d * E_DIM + c], accf);
    atomicAdd(&out[(size_t)s * E_DIM + c], accb);
}

extern "C" void kernel_launch(void* const* d_in, const int* in_sizes, int n_in,
                              void* d_out, int out_size, void* d_ws, size_t ws_size,
                              hipStream_t stream) {
    const int* edge_index = (const int*)d_in[0];   // [2][NE]
    const int* edge_type  = (const int*)d_in[1];   // [NE]
    const float* emb      = (const float*)d_in[2]; // [N][128]
    const float* weights  = (const float*)d_in[3]; // [L][18][128][128]
    const float* biases   = (const float*)d_in[4]; // [L][18][128]
    float* out = (float*)d_out;

    const int NE = in_sizes[1];
    const int Nn = in_sizes[2] / E_DIM;
    const int L  = in_sizes[3] / (2 * R_REL * E_DIM * E_DIM);

    const float* W2 = weights + (size_t)(L - 1) * 2 * R_REL * E_DIM * E_DIM;
    const float* B2 = biases  + (size_t)(L - 1) * 2 * R_REL * E_DIM;

    const int* esrc = edge_index;
    const int* edst = edge_index + NE;

    const size_t bufelems = (size_t)Nn * E_DIM;               // bf16 elements
    const size_t bufbytes = bufelems * sizeof(unsigned short);
    const int n2 = 2 * Nn;
    const int nb = (n2 + SCB - 1) / SCB;

    auto al = [](size_t x) { return (x + 255) & ~(size_t)255; };
    const size_t htBytes  = al(R_REL * bufbytes);             // 9 buffers
    const size_t wtBytes  = al((size_t)2 * R_REL * E_DIM * E_DIM * 2);
    const size_t offBytes = al((size_t)n2 * 4);
    const size_t curBytes = al((size_t)n2 * 4);
    const size_t recBytes = al((size_t)2 * NE * 4);
    const size_t bsBytes  = al((size_t)nb * 4);
    const size_t need = htBytes + wtBytes + offBytes + curBytes + recBytes + bsBytes;

    if (ws_size >= need) {
        char* p = (char*)d_ws;
        unsigned short* htB = (unsigned short*)p;        p += htBytes;
        unsigned short* Wt  = (unsigned short*)p;        p += wtBytes;
        int* off            = (int*)p;                   p += offBytes;
        int* cursor         = (int*)p;                   p += curBytes;
        unsigned* rec       = (unsigned*)p;              p += recBytes;
        int* bsum           = (int*)p;

        hipMemsetAsync(off, 0, (size_t)n2 * 4, stream);
        k_count8<<<8 * NSLICE, 256, 0, stream>>>(esrc, edst, off, NE, Nn);
        // Hierarchical scan: off(counts) -> off/cursor(exclusive prefixes).
        k_scan_part<<<nb, 256, 0, stream>>>(off, cursor, bsum, n2);
        k_scan_mid<<<1, 256, 0, stream>>>(bsum, nb);
        k_scan_apply<<<nb, 256, 0, stream>>>(cursor, bsum, off, cursor, n2);
        k_fill8<<<8 * NSLICE, 256, 0, stream>>>(esrc, edst, edge_type,
                                                cursor, rec, NE, Nn);
        w_swizzle<<<2 * R_REL, 256, 0, stream>>>(W2, Wt);

        const int ggrid = (Nn + GBM - 1) / GBM;
        // Pass 0: forward relations 0..8, segments [0, Nn), out = sum.
        gemm_all9<<<ggrid, 256, 0, stream>>>(emb, Wt, B2, htB, Nn, 0);
        k_gather<<<(Nn + 3) / 4, 256, 0, stream>>>(off, cursor, rec, htB, out,
                                                   Nn, 0, 0);
        // Pass 1: backward relations 9..17, segments [Nn, 2Nn), out += sum.
        gemm_all9<<<ggrid, 256, 0, stream>>>(emb, Wt, B2, htB, Nn, R_REL);
        k_gather<<<(Nn + 3) / 4, 256, 0, stream>>>(off, cursor, rec, htB, out,
                                                   Nn, Nn, 1);
        return;
    }

    // Fallbacks (round-2 behavior).
    hipMemsetAsync(d_out, 0, (size_t)Nn * E_DIM * sizeof(float), stream);
    const int nbuf = (int)(ws_size / bufbytes);
    if (nbuf >= 2) {
        const int PG = (nbuf / 2 < R_REL) ? (nbuf / 2) : R_REL;
        unsigned short* htB = (unsigned short*)d_ws;
        const int gx = (Nn + GBM * 4 - 1) / (GBM * 4);
        for (int p0 = 0; p0 < R_REL; ) {
            int pg = (R_REL - p0 < PG) ? (R_REL - p0) : PG;
            dim3 g1(gx, 2 * pg);
            gemm_bf16<<<g1, 256, 0, stream>>>(emb, W2, B2, htB, bufelems, p0, Nn);
            scatter_grp<<<(NE + 3) / 4, 256, 0, stream>>>(
                esrc, edst, edge_type, htB, bufelems, out, NE, p0, pg);
            p0 += pg;
        }
    } else {
        direct_edge<<<NE, 128, 0, stream>>>(esrc, edst, edge_type, emb, W2, B2, out, NE);
    }
}